// Round 1
// baseline (118.643 us; speedup 1.0000x reference)
//
#include <hip/hip_runtime.h>

// SWAP gate on qudits (DIM=2, WIRES=12, C=0, T=1): U is a permutation matrix
// swapping row-index bits 11 and 10. out = stack([U@x_real, U@x_imag]).
// Since the swap is an involution, out[i,:] = x[swapbits(i),:].
// Pure memory-bound permuted copy: 32 MiB in + 32 MiB out.

#define DD     4096   // D = 2^12
#define BB     1024   // BATCH
// float4s per plane = D*BATCH/4 = 2^20; row bits 10,11 -> float4-index bits 18,19
#define PLANE4 (DD * BB / 4)
#define TOTAL4 (2 * PLANE4)

__global__ __launch_bounds__(256) void swap_perm_kernel(
    const float4* __restrict__ xr,
    const float4* __restrict__ xi,
    float4* __restrict__ out)
{
    const unsigned g = blockIdx.x * 256u + threadIdx.x;   // [0, 2^21)
    const unsigned plane = g >> 20;                        // 0 = real, 1 = imag
    const unsigned w = g & (PLANE4 - 1u);                  // index within plane

    // swap bits 18 and 19 (== row bits 10 and 11)
    const unsigned b18 = (w >> 18) & 1u;
    const unsigned b19 = (w >> 19) & 1u;
    const unsigned src = (b18 != b19) ? (w ^ (3u << 18)) : w;

    const float4* __restrict__ in = plane ? xi : xr;
    out[g] = in[src];
}

extern "C" void kernel_launch(void* const* d_in, const int* in_sizes, int n_in,
                              void* d_out, int out_size, void* d_ws, size_t ws_size,
                              hipStream_t stream) {
    const float4* xr = (const float4*)d_in[0];
    const float4* xi = (const float4*)d_in[1];
    // d_in[2] is U — intentionally unused: the permutation is hardcoded.
    float4* out = (float4*)d_out;

    swap_perm_kernel<<<TOTAL4 / 256, 256, 0, stream>>>(xr, xi, out);
}

// Round 3
// 115.866 us; speedup vs baseline: 1.0240x; 1.0240x over previous
//
#include <hip/hip_runtime.h>

// SWAP gate on qudits (DIM=2, WIRES=12, C=0, T=1): U is a permutation matrix
// swapping row-index bits 11 and 10 of the 4096-row index; rows are 4 KiB
// contiguous, so in float4-index space (2^20 per plane) the swap hits bits
// 18 and 19. out[plane][w] = x[plane][w with bits18,19 swapped].
//
// Each thread owns one 18-bit low index and all four (b19,b18) quadrants of
// its plane: 4 independent coalesced 16B loads in flight, stored back with
// quadrants 01 and 10 exchanged in-register. Branchless, streaming stores.

typedef float v4f __attribute__((ext_vector_type(4)));

#define PLANE4 (4096 * 1024 / 4)   // 2^20 float4 per plane
#define QUAD4  (PLANE4 / 4)        // 2^18 float4 per quadrant

__global__ __launch_bounds__(256) void swap_perm_kernel(
    const v4f* __restrict__ xr,
    const v4f* __restrict__ xi,
    v4f* __restrict__ out)
{
    const unsigned g     = blockIdx.x * 256u + threadIdx.x;  // [0, 2^19)
    const unsigned plane = g >> 18;                          // 0 = real, 1 = imag
    const unsigned low   = g & (QUAD4 - 1u);                 // [0, 2^18)

    const v4f* __restrict__ in = plane ? xi : xr;
    v4f* __restrict__ o = out + plane * PLANE4 + low;

    const v4f v0 = in[low];                // quadrant 00
    const v4f v1 = in[low + 1u * QUAD4];   // quadrant 01 (b18=1)
    const v4f v2 = in[low + 2u * QUAD4];   // quadrant 10 (b19=1)
    const v4f v3 = in[low + 3u * QUAD4];   // quadrant 11

    __builtin_nontemporal_store(v0, o + 0u * QUAD4);
    __builtin_nontemporal_store(v2, o + 1u * QUAD4);  // dest 01 <- src 10
    __builtin_nontemporal_store(v1, o + 2u * QUAD4);  // dest 10 <- src 01
    __builtin_nontemporal_store(v3, o + 3u * QUAD4);
}

extern "C" void kernel_launch(void* const* d_in, const int* in_sizes, int n_in,
                              void* d_out, int out_size, void* d_ws, size_t ws_size,
                              hipStream_t stream) {
    const v4f* xr = (const v4f*)d_in[0];
    const v4f* xi = (const v4f*)d_in[1];
    // d_in[2] is U — intentionally unused: the permutation is hardcoded.
    v4f* out = (v4f*)d_out;

    swap_perm_kernel<<<(2 * QUAD4) / 256, 256, 0, stream>>>(xr, xi, out);
}